// Round 13
// baseline (1062.173 us; speedup 1.0000x reference)
//
#include <hip/hip_runtime.h>
#include <hip/hip_bf16.h>
#include <stdint.h>

#define TSTEPS 500
#define BB 32
#define N0 512
#define N1 1024
#define N2 512
#define PD 25
#define NCH 20

typedef __attribute__((ext_vector_type(8))) short short8;
typedef __attribute__((ext_vector_type(4))) float f32x4;

// ticket-role layout
#define TK_G1 64      // scan0: [0,64)
#define TK_S1 1064    // gemm1: [64,1064)  (125 m-tiles x 8 n)
#define TK_G2 1192    // scan1: [1064,1192)
#define TK_S2 1692    // gemm2: [1192,1692) (125 x 4)
#define NB_ALL 1756   // scan2: [1692,1756)

// ---------------- flag primitives (agent scope, release/acquire) ----------
__device__ __forceinline__ void waitf(uint32_t* f, uint32_t tgt) {
    if (threadIdx.x == 0) {
        while (__hip_atomic_load(f, __ATOMIC_RELAXED, __HIP_MEMORY_SCOPE_AGENT) < tgt)
            __builtin_amdgcn_s_sleep(8);
        (void)__hip_atomic_load(f, __ATOMIC_ACQUIRE, __HIP_MEMORY_SCOPE_AGENT);
    }
    __syncthreads();
}
__device__ __forceinline__ void postf(uint32_t* f) {
    __syncthreads();  // drains each wave's stores (vmcnt0) before release
    if (threadIdx.x == 0)
        __hip_atomic_fetch_add(f, 1u, __ATOMIC_RELEASE, __HIP_MEMORY_SCOPE_AGENT);
}

// ---------------- GLIFR step (unchanged arithmetic) ------------------------
__device__ __forceinline__ float glifr_step(float& v, float& a0, float& a1,
                                            float x) {
    const float INV_I0 = 1.0f / 700.0f;
    const float C2 = 9.43f / 700.0f;
    const float CE = 0.14426950408889634f;
    const float CE10 = 1.4426950408889634f;
    const float C0 = 1.0f - 0.05f * 0.003f;
    const float C1 = 1.0f - 0.05f * 0.1f;
    const float AMP0 = -9.18f, AMP1 = -198.94f;
    float asum = a0 + a1;
    float drv = fmaf(asum, INV_I0, x);
    float e = exp2f(fmaf(v, -CE, CE10));
    float sig = __builtin_amdgcn_rcpf(1.0f + e);
    float na0 = fmaf(sig, a0 + AMP0, a0 * C0);
    float na1 = fmaf(sig, a1 + AMP1, a1 * C1);
    float nv = fmaf(-sig, v, fmaf(-C2, v, v + drv));
    a0 = na0; a1 = na1; v = nv;
    return sig;
}

// ---------------- scan role -------------------------------------------------
// MODE 0: drive[t] (inputs), packed out, posts fo[chunk] (==64)
// MODE 1: drive[t-1] (x1), packed out (SKIPS t=499 store: flag tail), waits
//         per-tile f1 (==8) monotonically, posts fo[chunk] (==128)
// MODE 2: drive[t-1] (x2==out), f32 out (20*sig), waits f2 (==4); wait index
//         covers its own STORE rows: (800c+799)>>7.
template <int NW, int MODE>
__device__ void scan_role(const float* drive, uint32_t* pout, float* fout,
                          int idx, uint32_t* ftile, uint32_t ftgt,
                          uint32_t* fo) {
    const int S = BB * NW;
    float v = 0.f, a0 = 0.f, a1 = 0.f;
    int mdone = -1;

    auto wait_chunk = [&](int c) {
        if (MODE == 0) return;
        const int M = (MODE == 1) ? ((800 * c + 767) >> 7)
                                  : ((800 * c + 799) >> 7);
        while (mdone < M) { ++mdone; waitf(&ftile[mdone], ftgt); }
    };
    auto LD = [&](int t) -> float {
        if (MODE == 0) return drive[(size_t)t * S + idx];
        return drive[(size_t)(t - 1) * S + idx];
    };
    auto STEP = [&](int t, float x) {
        float sig = glifr_step(v, a0, a1, x);
        size_t o = (size_t)t * S + idx;
        if (MODE == 2) {
            fout[o] = 20.0f * sig;
        } else {
            if (MODE == 1 && t == TSTEPS - 1) return;  // s1 tail = flag space
            uint32_t su = __float_as_uint(sig);
            float lo = sig - __uint_as_float(su & 0xffff0000u);
            pout[o] = (su >> 16) | (__float_as_uint(lo) & 0xffff0000u);
        }
    };

    float p[PD], q[PD];
    wait_chunk(0);
#pragma unroll
    for (int i = 0; i < PD; ++i)
        p[i] = (MODE != 0 && i == 0) ? 0.0f : LD(i);

    for (int c = 0; c < NCH - 1; ++c) {
        wait_chunk(c + 1);
#pragma unroll
        for (int i = 0; i < PD; ++i) q[i] = LD(25 * (c + 1) + i);
#pragma unroll
        for (int i = 0; i < PD; ++i) STEP(25 * c + i, p[i]);
        if (MODE != 2) postf(&fo[c]);
#pragma unroll
        for (int i = 0; i < PD; ++i) p[i] = q[i];
    }
#pragma unroll
    for (int i = 0; i < PD; ++i) STEP(25 * (NCH - 1) + i, p[i]);
    if (MODE != 2) postf(&fo[NCH - 1]);
}

// ---------------- gemm role -------------------------------------------------
// bf16x3 MFMA GEMM tile: A packed u32 planes (v_perm split), B split in-kernel
// from f32 W (x20), both reg-staged into double-buffered 64KB LDS with the
// proven conflict-free swizzle. Waits its A rows on fin; posts fo[m].
template <int NBY, int KC>
__device__ void gemm_role(const uint32_t* Apk, const float* W, float* C,
                          int g, uint32_t* fin, uint32_t ftgt, uint32_t* fo,
                          char* lds) {
    constexpr int NC = NBY * 128;
    constexpr int KSTEPS = KC / 32;
    const int tid = threadIdx.x;
    const int lane = tid & 63, wave = tid >> 6;
    const int m = g / NBY, n = g % NBY;  // m-major: ticket order ~ time order
    const int m0 = m * 128, n0 = n * 128;

    waitf(&fin[(4 * m + 3) / 25], ftgt);

    // A staging geometry (round-9 proven)
    const int r0 = tid >> 3, c4 = tid & 7;
    const int ch = (c4 >> 1) ^ ((r0 >> 1) & 3);
    const int aoff = r0 * 64 + ch * 16 + (c4 & 1) * 8;
    const uint32_t* aSrc = Apk + (size_t)(m0 + r0) * KC + c4 * 4;

    // B staging: swizzle-matched LINEAR writes (thread t owns hi-plane slot t)
    const int bR = tid >> 2, bS = tid & 3;
    const int bKC = bS ^ ((bR >> 1) & 3);           // k-chunk for rows bR,bR+64
    const float* wSrc = W + (size_t)(n0 + bR) * KC + bKC * 8;

    const int wm = wave >> 1, wn = wave & 1;
    const int r4 = lane & 15, kg = lane >> 4;
    const int slot = kg ^ ((r4 >> 1) & 3);
    const int fA = (wm * 64 + r4) * 64 + slot * 16;
    const int fBr = 16384 + (wn * 64 + r4) * 64 + slot * 16;

    f32x4 acc[4][4];
#pragma unroll
    for (int i = 0; i < 4; ++i)
#pragma unroll
        for (int j = 0; j < 4; ++j) acc[i][j] = (f32x4){0.f, 0.f, 0.f, 0.f};

    auto loadA = [&](int ks, uint4* R) {
#pragma unroll
        for (int i = 0; i < 4; ++i)
            R[i] = *reinterpret_cast<const uint4*>(
                aSrc + (size_t)i * 32 * KC + (size_t)ks * 32);
    };
    auto loadB = [&](int ks, float4* F) {
        const float* p = wSrc + ks * 32;
        F[0] = *reinterpret_cast<const float4*>(p);
        F[1] = *reinterpret_cast<const float4*>(p + 4);
        F[2] = *reinterpret_cast<const float4*>(p + (size_t)64 * KC);
        F[3] = *reinterpret_cast<const float4*>(p + (size_t)64 * KC + 4);
    };
    auto writeA = [&](const uint4* R, int buf) {
        char* base = lds + buf * 32768;
#pragma unroll
        for (int i = 0; i < 4; ++i) {
            uint32_t hi01 = __builtin_amdgcn_perm(R[i].y, R[i].x, 0x05040100u);
            uint32_t lo01 = __builtin_amdgcn_perm(R[i].y, R[i].x, 0x07060302u);
            uint32_t hi23 = __builtin_amdgcn_perm(R[i].w, R[i].z, 0x05040100u);
            uint32_t lo23 = __builtin_amdgcn_perm(R[i].w, R[i].z, 0x07060302u);
            *reinterpret_cast<uint2*>(base + aoff + i * 2048) =
                make_uint2(hi01, hi23);
            *reinterpret_cast<uint2*>(base + 8192 + aoff + i * 2048) =
                make_uint2(lo01, lo23);
        }
    };
    auto writeB = [&](const float4* F, int buf) {
        char* bh = lds + buf * 32768 + 16384;
#pragma unroll
        for (int r = 0; r < 2; ++r) {
            float f[8] = {20.0f * F[2 * r].x, 20.0f * F[2 * r].y,
                          20.0f * F[2 * r].z, 20.0f * F[2 * r].w,
                          20.0f * F[2 * r + 1].x, 20.0f * F[2 * r + 1].y,
                          20.0f * F[2 * r + 1].z, 20.0f * F[2 * r + 1].w};
            uint32_t H[4], L[4];
#pragma unroll
            for (int p2 = 0; p2 < 4; ++p2) {
                __hip_bfloat162 h = __float22bfloat162_rn(
                    make_float2(f[2 * p2], f[2 * p2 + 1]));
                H[p2] = *reinterpret_cast<uint32_t*>(&h);
                float l0 = f[2 * p2] - __uint_as_float(H[p2] << 16);
                float l1 = f[2 * p2 + 1] - __uint_as_float(H[p2] & 0xffff0000u);
                __hip_bfloat162 lw = __float22bfloat162_rn(make_float2(l0, l1));
                L[p2] = *reinterpret_cast<uint32_t*>(&lw);
            }
            *reinterpret_cast<uint4*>(bh + r * 4096 + tid * 16) =
                make_uint4(H[0], H[1], H[2], H[3]);
            *reinterpret_cast<uint4*>(bh + 8192 + r * 4096 + tid * 16) =
                make_uint4(L[0], L[1], L[2], L[3]);
        }
    };
    auto compute = [&](int buf) {
        char* base = lds + buf * 32768;
        short8 ah[4], al[4], bh[4], bl[4];
#pragma unroll
        for (int i = 0; i < 4; ++i) {
            ah[i] = *(const short8*)(base + fA + i * 1024);
            al[i] = *(const short8*)(base + 8192 + fA + i * 1024);
            bh[i] = *(const short8*)(base + fBr + i * 1024);
            bl[i] = *(const short8*)(base + fBr + 8192 + i * 1024);
        }
#pragma unroll
        for (int i = 0; i < 4; ++i)
#pragma unroll
            for (int j = 0; j < 4; ++j) {
                acc[i][j] = __builtin_amdgcn_mfma_f32_16x16x32_bf16(
                    ah[i], bh[j], acc[i][j], 0, 0, 0);
                acc[i][j] = __builtin_amdgcn_mfma_f32_16x16x32_bf16(
                    ah[i], bl[j], acc[i][j], 0, 0, 0);
                acc[i][j] = __builtin_amdgcn_mfma_f32_16x16x32_bf16(
                    al[i], bh[j], acc[i][j], 0, 0, 0);
            }
    };
    auto bar = [&]() {
        asm volatile("s_waitcnt lgkmcnt(0)" ::: "memory");
        __builtin_amdgcn_s_barrier();
        __builtin_amdgcn_sched_barrier(0);
    };

    uint4 RA[4]; float4 RB[4];
    loadA(0, RA); loadB(0, RB);
    writeA(RA, 0); writeB(RB, 0);
    bar();
    for (int s = 0; s < KSTEPS - 1; ++s) {
        loadA(s + 1, RA);
        loadB(s + 1, RB);
        compute(s & 1);
        writeA(RA, (s + 1) & 1);
        writeB(RB, (s + 1) & 1);
        bar();
    }
    compute((KSTEPS - 1) & 1);

#pragma unroll
    for (int i = 0; i < 4; ++i)
#pragma unroll
        for (int j = 0; j < 4; ++j)
#pragma unroll
            for (int r = 0; r < 4; ++r) {
                int row = m0 + wm * 64 + i * 16 + kg * 4 + r;
                int col = n0 + wn * 64 + j * 16 + r4;
                C[(size_t)row * NC + col] = acc[i][j][r];
            }
    postf(&fo[m]);
}

// ---------------- persistent mega-kernel -----------------------------------
__global__ __launch_bounds__(256, 2) void snn_mega(
    const float* inputs, const float* W1, const float* W2,
    uint32_t* s0, float* x1, uint32_t* s1, float* out, uint32_t* flags) {
    __shared__ char lds[65536];
    __shared__ uint32_t tkv;
    if (threadIdx.x == 0)
        tkv = __hip_atomic_fetch_add(&flags[0], 1u, __ATOMIC_RELAXED,
                                     __HIP_MEMORY_SCOPE_AGENT);
    __syncthreads();
    const uint32_t tk = tkv;
    uint32_t* f0  = flags + 8;    // [20]  scan0 chunks, tgt 64
    uint32_t* f1  = flags + 32;   // [125] gemm1 m-tiles, tgt 8
    uint32_t* f1s = flags + 160;  // [20]  scan1 chunks, tgt 128
    uint32_t* f2  = flags + 184;  // [125] gemm2 m-tiles, tgt 4

    if (tk < TK_G1) {
        scan_role<N0, 0>(inputs, s0, nullptr, tk * 256 + threadIdx.x,
                         nullptr, 0u, f0);
    } else if (tk < TK_S1) {
        gemm_role<8, N0>(s0, W1, x1, (int)(tk - TK_G1), f0, 64u, f1, lds);
    } else if (tk < TK_G2) {
        scan_role<N1, 1>(x1, s1, nullptr, (tk - TK_S1) * 256 + threadIdx.x,
                         f1, 8u, f1s);
    } else if (tk < TK_S2) {
        gemm_role<4, N1>(s1, W2, out, (int)(tk - TK_G2), f1s, 128u, f2, lds);
    } else {
        scan_role<N2, 2>(out, nullptr, out, (tk - TK_S2) * 256 + threadIdx.x,
                         f2, 4u, nullptr);
    }
}

extern "C" void kernel_launch(void* const* d_in, const int* in_sizes, int n_in,
                              void* d_out, int out_size, void* d_ws,
                              size_t ws_size, hipStream_t stream) {
    const float* inputs = (const float*)d_in[0];  // [500,32,512]
    const float* W1 = (const float*)d_in[1];      // [1024,512]
    const float* W2 = (const float*)d_in[2];      // [512,1024]
    float* out = (float*)d_out;                   // [500,32,512]; doubles as x2
    char* ws = (char*)d_ws;

    // ws layout (bytes), total 163,840,000 (proven bound from round 1):
    //  s0: [0, 32,768,000)           packed u32 [16000,512]
    //  x1: [32,768,000, 98,304,000)  f32 [16000,1024]
    //  s1: [98,304,000, 163,840,000) packed u32 [16000,1024];
    //      rows 15968..15999 (t=499, provably unread) hold the flags.
    uint32_t* s0 = (uint32_t*)ws;
    float*    x1 = (float*)(ws + 32768000);
    uint32_t* s1 = (uint32_t*)(ws + 98304000);
    uint32_t* flags = (uint32_t*)(ws + 163708928);  // s1 row 15968

    hipMemsetAsync(flags, 0, 4096, stream);
    snn_mega<<<NB_ALL, 256, 0, stream>>>(inputs, W1, W2, s0, x1, s1, out,
                                         flags);
}

// Round 14
// 567.829 us; speedup vs baseline: 1.8706x; 1.8706x over previous
//
#include <hip/hip_runtime.h>
#include <hip/hip_bf16.h>
#include <stdint.h>

#define TSTEPS 500
#define BB 32
#define N0 512
#define N1 1024
#define N2 512
#define PD 25
#define NCH 20

typedef __attribute__((ext_vector_type(8))) short short8;
typedef __attribute__((ext_vector_type(4))) float f32x4;

// ticket-role layout
#define TK_G1 64      // scan0: [0,64)
#define TK_S1 1064    // gemm1: [64,1064)  (125 m-tiles x 8 n)
#define TK_G2 1192    // scan1: [1064,1192)
#define TK_S2 1692    // gemm2: [1192,1692) (125 x 4)
#define NB_ALL 1756   // scan2: [1692,1756)
#define NPERS 512     // persistent blocks (2/CU)

// flags: each flag on its own 64B line (16 u32 stride) to kill line-bounce.
// flags[0] = ticket counter. f0 @ +16, f1 @ +336, f1s @ +2336, f2 @ +2656.
#define FPAD 16

// ---------------- flag primitives (agent scope, release/acquire) ----------
__device__ __forceinline__ void waitf(uint32_t* f, uint32_t tgt) {
    if (threadIdx.x == 0) {
        while (__hip_atomic_load(f, __ATOMIC_RELAXED, __HIP_MEMORY_SCOPE_AGENT) < tgt)
            __builtin_amdgcn_s_sleep(32);
        (void)__hip_atomic_load(f, __ATOMIC_ACQUIRE, __HIP_MEMORY_SCOPE_AGENT);
    }
    __syncthreads();
}
__device__ __forceinline__ void postf(uint32_t* f) {
    __syncthreads();  // each thread drains its stores (vmcnt0) at the barrier
    if (threadIdx.x == 0)
        __hip_atomic_fetch_add(f, 1u, __ATOMIC_RELEASE, __HIP_MEMORY_SCOPE_AGENT);
}

// ---------------- GLIFR step (unchanged arithmetic) ------------------------
__device__ __forceinline__ float glifr_step(float& v, float& a0, float& a1,
                                            float x) {
    const float INV_I0 = 1.0f / 700.0f;
    const float C2 = 9.43f / 700.0f;
    const float CE = 0.14426950408889634f;
    const float CE10 = 1.4426950408889634f;
    const float C0 = 1.0f - 0.05f * 0.003f;
    const float C1 = 1.0f - 0.05f * 0.1f;
    const float AMP0 = -9.18f, AMP1 = -198.94f;
    float asum = a0 + a1;
    float drv = fmaf(asum, INV_I0, x);
    float e = exp2f(fmaf(v, -CE, CE10));
    float sig = __builtin_amdgcn_rcpf(1.0f + e);
    float na0 = fmaf(sig, a0 + AMP0, a0 * C0);
    float na1 = fmaf(sig, a1 + AMP1, a1 * C1);
    float nv = fmaf(-sig, v, fmaf(-C2, v, v + drv));
    a0 = na0; a1 = na1; v = nv;
    return sig;
}

// ---------------- scan role (identical logic to r13, flags padded) ---------
template <int NW, int MODE>
__device__ void scan_role(const float* drive, uint32_t* pout, float* fout,
                          int idx, uint32_t* ftile, uint32_t ftgt,
                          uint32_t* fo) {
    const int S = BB * NW;
    float v = 0.f, a0 = 0.f, a1 = 0.f;
    int mdone = -1;

    auto wait_chunk = [&](int c) {
        if (MODE == 0) return;
        const int M = (MODE == 1) ? ((800 * c + 767) >> 7)
                                  : ((800 * c + 799) >> 7);
        while (mdone < M) { ++mdone; waitf(&ftile[mdone * FPAD], ftgt); }
    };
    auto LD = [&](int t) -> float {
        if (MODE == 0) return drive[(size_t)t * S + idx];
        return drive[(size_t)(t - 1) * S + idx];
    };
    auto STEP = [&](int t, float x) {
        float sig = glifr_step(v, a0, a1, x);
        size_t o = (size_t)t * S + idx;
        if (MODE == 2) {
            fout[o] = 20.0f * sig;
        } else {
            if (MODE == 1 && t == TSTEPS - 1) return;  // s1 tail = flag space
            uint32_t su = __float_as_uint(sig);
            float lo = sig - __uint_as_float(su & 0xffff0000u);
            pout[o] = (su >> 16) | (__float_as_uint(lo) & 0xffff0000u);
        }
    };

    float p[PD], q[PD];
    wait_chunk(0);
#pragma unroll
    for (int i = 0; i < PD; ++i)
        p[i] = (MODE != 0 && i == 0) ? 0.0f : LD(i);

    for (int c = 0; c < NCH - 1; ++c) {
        wait_chunk(c + 1);
#pragma unroll
        for (int i = 0; i < PD; ++i) q[i] = LD(25 * (c + 1) + i);
#pragma unroll
        for (int i = 0; i < PD; ++i) STEP(25 * c + i, p[i]);
        if (MODE != 2) postf(&fo[c * FPAD]);
#pragma unroll
        for (int i = 0; i < PD; ++i) p[i] = q[i];
    }
#pragma unroll
    for (int i = 0; i < PD; ++i) STEP(25 * (NCH - 1) + i, p[i]);
    if (MODE != 2) postf(&fo[(NCH - 1) * FPAD]);
}

// ---------------- gemm role (identical to r13, flags padded) ---------------
template <int NBY, int KC>
__device__ void gemm_role(const uint32_t* Apk, const float* W, float* C,
                          int g, uint32_t* fin, uint32_t ftgt, uint32_t* fo,
                          char* lds) {
    constexpr int NC = NBY * 128;
    constexpr int KSTEPS = KC / 32;
    const int tid = threadIdx.x;
    const int lane = tid & 63, wave = tid >> 6;
    const int m = g / NBY, n = g % NBY;
    const int m0 = m * 128, n0 = n * 128;

    waitf(&fin[((4 * m + 3) / 25) * FPAD], ftgt);

    const int r0 = tid >> 3, c4 = tid & 7;
    const int ch = (c4 >> 1) ^ ((r0 >> 1) & 3);
    const int aoff = r0 * 64 + ch * 16 + (c4 & 1) * 8;
    const uint32_t* aSrc = Apk + (size_t)(m0 + r0) * KC + c4 * 4;

    const int bR = tid >> 2, bS = tid & 3;
    const int bKC = bS ^ ((bR >> 1) & 3);
    const float* wSrc = W + (size_t)(n0 + bR) * KC + bKC * 8;

    const int wm = wave >> 1, wn = wave & 1;
    const int r4 = lane & 15, kg = lane >> 4;
    const int slot = kg ^ ((r4 >> 1) & 3);
    const int fA = (wm * 64 + r4) * 64 + slot * 16;
    const int fBr = 16384 + (wn * 64 + r4) * 64 + slot * 16;

    f32x4 acc[4][4];
#pragma unroll
    for (int i = 0; i < 4; ++i)
#pragma unroll
        for (int j = 0; j < 4; ++j) acc[i][j] = (f32x4){0.f, 0.f, 0.f, 0.f};

    auto loadA = [&](int ks, uint4* R) {
#pragma unroll
        for (int i = 0; i < 4; ++i)
            R[i] = *reinterpret_cast<const uint4*>(
                aSrc + (size_t)i * 32 * KC + (size_t)ks * 32);
    };
    auto loadB = [&](int ks, float4* F) {
        const float* p = wSrc + ks * 32;
        F[0] = *reinterpret_cast<const float4*>(p);
        F[1] = *reinterpret_cast<const float4*>(p + 4);
        F[2] = *reinterpret_cast<const float4*>(p + (size_t)64 * KC);
        F[3] = *reinterpret_cast<const float4*>(p + (size_t)64 * KC + 4);
    };
    auto writeA = [&](const uint4* R, int buf) {
        char* base = lds + buf * 32768;
#pragma unroll
        for (int i = 0; i < 4; ++i) {
            uint32_t hi01 = __builtin_amdgcn_perm(R[i].y, R[i].x, 0x05040100u);
            uint32_t lo01 = __builtin_amdgcn_perm(R[i].y, R[i].x, 0x07060302u);
            uint32_t hi23 = __builtin_amdgcn_perm(R[i].w, R[i].z, 0x05040100u);
            uint32_t lo23 = __builtin_amdgcn_perm(R[i].w, R[i].z, 0x07060302u);
            *reinterpret_cast<uint2*>(base + aoff + i * 2048) =
                make_uint2(hi01, hi23);
            *reinterpret_cast<uint2*>(base + 8192 + aoff + i * 2048) =
                make_uint2(lo01, lo23);
        }
    };
    auto writeB = [&](const float4* F, int buf) {
        char* bh = lds + buf * 32768 + 16384;
#pragma unroll
        for (int r = 0; r < 2; ++r) {
            float f[8] = {20.0f * F[2 * r].x, 20.0f * F[2 * r].y,
                          20.0f * F[2 * r].z, 20.0f * F[2 * r].w,
                          20.0f * F[2 * r + 1].x, 20.0f * F[2 * r + 1].y,
                          20.0f * F[2 * r + 1].z, 20.0f * F[2 * r + 1].w};
            uint32_t H[4], L[4];
#pragma unroll
            for (int p2 = 0; p2 < 4; ++p2) {
                __hip_bfloat162 h = __float22bfloat162_rn(
                    make_float2(f[2 * p2], f[2 * p2 + 1]));
                H[p2] = *reinterpret_cast<uint32_t*>(&h);
                float l0 = f[2 * p2] - __uint_as_float(H[p2] << 16);
                float l1 = f[2 * p2 + 1] - __uint_as_float(H[p2] & 0xffff0000u);
                __hip_bfloat162 lw = __float22bfloat162_rn(make_float2(l0, l1));
                L[p2] = *reinterpret_cast<uint32_t*>(&lw);
            }
            *reinterpret_cast<uint4*>(bh + r * 4096 + tid * 16) =
                make_uint4(H[0], H[1], H[2], H[3]);
            *reinterpret_cast<uint4*>(bh + 8192 + r * 4096 + tid * 16) =
                make_uint4(L[0], L[1], L[2], L[3]);
        }
    };
    auto compute = [&](int buf) {
        char* base = lds + buf * 32768;
        short8 ah[4], al[4], bh[4], bl[4];
#pragma unroll
        for (int i = 0; i < 4; ++i) {
            ah[i] = *(const short8*)(base + fA + i * 1024);
            al[i] = *(const short8*)(base + 8192 + fA + i * 1024);
            bh[i] = *(const short8*)(base + fBr + i * 1024);
            bl[i] = *(const short8*)(base + fBr + 8192 + i * 1024);
        }
#pragma unroll
        for (int i = 0; i < 4; ++i)
#pragma unroll
            for (int j = 0; j < 4; ++j) {
                acc[i][j] = __builtin_amdgcn_mfma_f32_16x16x32_bf16(
                    ah[i], bh[j], acc[i][j], 0, 0, 0);
                acc[i][j] = __builtin_amdgcn_mfma_f32_16x16x32_bf16(
                    ah[i], bl[j], acc[i][j], 0, 0, 0);
                acc[i][j] = __builtin_amdgcn_mfma_f32_16x16x32_bf16(
                    al[i], bh[j], acc[i][j], 0, 0, 0);
            }
    };
    auto bar = [&]() {
        asm volatile("s_waitcnt lgkmcnt(0)" ::: "memory");
        __builtin_amdgcn_s_barrier();
        __builtin_amdgcn_sched_barrier(0);
    };

    uint4 RA[4]; float4 RB[4];
    loadA(0, RA); loadB(0, RB);
    writeA(RA, 0); writeB(RB, 0);
    bar();
    for (int s = 0; s < KSTEPS - 1; ++s) {
        loadA(s + 1, RA);
        loadB(s + 1, RB);
        compute(s & 1);
        writeA(RA, (s + 1) & 1);
        writeB(RB, (s + 1) & 1);
        bar();
    }
    compute((KSTEPS - 1) & 1);

#pragma unroll
    for (int i = 0; i < 4; ++i)
#pragma unroll
        for (int j = 0; j < 4; ++j)
#pragma unroll
            for (int r = 0; r < 4; ++r) {
                int row = m0 + wm * 64 + i * 16 + kg * 4 + r;
                int col = n0 + wn * 64 + j * 16 + r4;
                C[(size_t)row * NC + col] = acc[i][j][r];
            }
    postf(&fo[m * FPAD]);
}

// ---------------- persistent mega-kernel (ticket loop) ---------------------
__global__ __launch_bounds__(256, 2) void snn_mega(
    const float* inputs, const float* W1, const float* W2,
    uint32_t* s0, float* x1, uint32_t* s1, float* out, uint32_t* flags) {
    __shared__ char lds[65536];
    __shared__ uint32_t tkv;
    uint32_t* f0  = flags + 16;
    uint32_t* f1  = flags + 336;
    uint32_t* f1s = flags + 2336;
    uint32_t* f2  = flags + 2656;

    for (;;) {
        __syncthreads();  // protect lds/tkv reuse across tickets
        if (threadIdx.x == 0)
            tkv = __hip_atomic_fetch_add(&flags[0], 1u, __ATOMIC_RELAXED,
                                         __HIP_MEMORY_SCOPE_AGENT);
        __syncthreads();
        const uint32_t tk = tkv;
        if (tk >= NB_ALL) return;

        if (tk < TK_G1) {
            scan_role<N0, 0>(inputs, s0, nullptr, tk * 256 + threadIdx.x,
                             nullptr, 0u, f0);
        } else if (tk < TK_S1) {
            gemm_role<8, N0>(s0, W1, x1, (int)(tk - TK_G1), f0, 64u, f1, lds);
        } else if (tk < TK_G2) {
            scan_role<N1, 1>(x1, s1, nullptr,
                             (tk - TK_S1) * 256 + threadIdx.x, f1, 8u, f1s);
        } else if (tk < TK_S2) {
            gemm_role<4, N1>(s1, W2, out, (int)(tk - TK_G2), f1s, 128u, f2,
                             lds);
        } else {
            scan_role<N2, 2>(out, nullptr, out,
                             (tk - TK_S2) * 256 + threadIdx.x, f2, 4u,
                             nullptr);
        }
    }
}

extern "C" void kernel_launch(void* const* d_in, const int* in_sizes, int n_in,
                              void* d_out, int out_size, void* d_ws,
                              size_t ws_size, hipStream_t stream) {
    const float* inputs = (const float*)d_in[0];  // [500,32,512]
    const float* W1 = (const float*)d_in[1];      // [1024,512]
    const float* W2 = (const float*)d_in[2];      // [512,1024]
    float* out = (float*)d_out;                   // [500,32,512]; doubles as x2
    char* ws = (char*)d_ws;

    // ws layout (bytes):
    //  s0: [0, 32,768,000)           packed u32 [16000,512]
    //  x1: [32,768,000, 98,304,000)  f32 [16000,1024]
    //  s1: [98,304,000, 163,840,000) packed u32 [16000,1024];
    //      rows 15968.. (t=499, provably unread) hold the padded flags.
    uint32_t* s0 = (uint32_t*)ws;
    float*    x1 = (float*)(ws + 32768000);
    uint32_t* s1 = (uint32_t*)(ws + 98304000);
    uint32_t* flags = (uint32_t*)(ws + 163708928);  // s1 row 15968, 128KB free

    hipMemsetAsync(flags, 0, 32768, stream);
    snn_mega<<<NPERS, 256, 0, stream>>>(inputs, W1, W2, s0, x1, s1, out,
                                        flags);
}

// Round 15
// 201.791 us; speedup vs baseline: 5.2637x; 2.8139x over previous
//
#include <hip/hip_runtime.h>
#include <hip/hip_bf16.h>
#include <stdint.h>

#define TSTEPS 500
#define BB 32
#define N0 512
#define N1 1024
#define N2 512

typedef unsigned short ushort_t;
typedef __attribute__((ext_vector_type(8))) short short8;
typedef __attribute__((ext_vector_type(4))) float f32x4;

// ---------------- bf16 helpers --------------------------------------------
__device__ __forceinline__ ushort_t f2b(float x) {
    union { float f; uint32_t u; } c; c.f = x;
    uint32_t r = (c.u + 0x7fffu + ((c.u >> 16) & 1u)) >> 16;
    return (ushort_t)r;
}
__device__ __forceinline__ float b2f(ushort_t u) {
    union { uint32_t u; float f; } c; c.u = ((uint32_t)u) << 16;
    return c.f;
}

// ---------------- GLIFR step, algebraically reduced ------------------------
__device__ __forceinline__ float glifr_step(float& v, float& a0, float& a1,
                                            float x) {
    const float INV_I0 = 1.0f / 700.0f;
    const float C2 = 9.43f / 700.0f;
    const float CE = 0.14426950408889634f;
    const float CE10 = 1.4426950408889634f;
    const float C0 = 1.0f - 0.05f * 0.003f;
    const float C1 = 1.0f - 0.05f * 0.1f;
    const float AMP0 = -9.18f, AMP1 = -198.94f;

    float asum = a0 + a1;
    float drv = fmaf(asum, INV_I0, x);
    float e = exp2f(fmaf(v, -CE, CE10));
    float sig = __builtin_amdgcn_rcpf(1.0f + e);
    float na0 = fmaf(sig, a0 + AMP0, a0 * C0);
    float na1 = fmaf(sig, a1 + AMP1, a1 * C1);
    float nv = fmaf(-sig, v, fmaf(-C2, v, v + drv));
    a0 = na0; a1 = na1; v = nv;
    return sig;
}

// ---------------- scan body: round-9 proven rolling PD=25 prefetch ---------
#define PD 25
template <int NW, int MODE>
__device__ __forceinline__ void scan_body(const float* __restrict__ drive,
                                          uint32_t* __restrict__ pout,
                                          float* __restrict__ fout, int idx) {
    const int S = BB * NW;

    auto LD = [&](int t) -> float {
        if (MODE == 0) return drive[(size_t)t * S + idx];
        return (t == 0) ? 0.0f : drive[(size_t)(t - 1) * S + idx];
    };

    float v = 0.f, a0 = 0.f, a1 = 0.f;

    auto STEP = [&](int t, float x) {
        float sig = glifr_step(v, a0, a1, x);
        size_t o = (size_t)t * S + idx;
        if (MODE == 2) {
            fout[o] = 20.0f * sig;
        } else {
            uint32_t su = __float_as_uint(sig);
            float lo = sig - __uint_as_float(su & 0xffff0000u);
            pout[o] = (su >> 16) | (__float_as_uint(lo) & 0xffff0000u);
        }
    };

    float p[PD];
#pragma unroll
    for (int i = 0; i < PD; ++i) p[i] = LD(i);

    for (int t = 0; t < TSTEPS - PD; t += PD) {
        float q[PD];
#pragma unroll
        for (int i = 0; i < PD; ++i) q[i] = LD(t + PD + i);
#pragma unroll
        for (int i = 0; i < PD; ++i) STEP(t + i, p[i]);
#pragma unroll
        for (int i = 0; i < PD; ++i) p[i] = q[i];
    }
#pragma unroll
    for (int i = 0; i < PD; ++i) STEP(TSTEPS - PD + i, p[i]);
}

// ---------------- scan0 fused with weight split ----------------------------
__global__ __launch_bounds__(64, 1) void scan0_wsplit(
    const float* __restrict__ inputs, uint32_t* __restrict__ s0,
    const float* __restrict__ W1, const float* __restrict__ W2,
    ushort_t* __restrict__ w1h, ushort_t* __restrict__ w1l,
    ushort_t* __restrict__ w2h, ushort_t* __restrict__ w2l) {
    const int bid = blockIdx.x;
    if (bid < (BB * N0) / 64) {
        scan_body<N0, 0>(inputs, s0, nullptr, bid * 64 + threadIdx.x);
    } else {
        int i = (bid - (BB * N0) / 64) * 64 + threadIdx.x;
        float a = 20.0f * W1[i];
        ushort_t h = f2b(a);
        w1h[i] = h; w1l[i] = f2b(a - b2f(h));
        float b = 20.0f * W2[i];
        h = f2b(b);
        w2h[i] = h; w2l[i] = f2b(b - b2f(h));
    }
}

template <int NW>
__global__ __launch_bounds__(64, 1) void scan_mid(
    const float* __restrict__ drive, uint32_t* __restrict__ sout) {
    scan_body<NW, 1>(drive, sout, nullptr,
                     blockIdx.x * blockDim.x + threadIdx.x);
}

__global__ __launch_bounds__(64, 1) void scan_last(
    const float* __restrict__ drive, float* __restrict__ out) {
    scan_body<N2, 2>(drive, nullptr, out,
                     blockIdx.x * blockDim.x + threadIdx.x);
}

// ---------------- bf16x3-split MFMA GEMM, deep-pipelined (round 9) ---------
template <int NBY, int KC>
__global__ __launch_bounds__(256, 2) void gemm_x3(
    const uint32_t* __restrict__ Apk,
    const ushort_t* __restrict__ Bh, const ushort_t* __restrict__ Bl,
    float* __restrict__ C) {
    constexpr int NC = NBY * 128;
    constexpr int KSTEPS = KC / 32;   // 16 or 32 (even)
    __shared__ char lds[81920];       // A: 2x16KB @0 ; B: 3x16KB @32768
    const int tid = threadIdx.x;
    const int lane = tid & 63, wave = tid >> 6;

    // bijective XCD swizzle (m204)
    const int id = blockIdx.x, nwg = gridDim.x;
    const int qq = nwg >> 3, rr = nwg & 7;
    const int xcd = id & 7, jj = id >> 3;
    const int wg = (xcd < rr ? xcd * (qq + 1) : rr * (qq + 1) + (xcd - rr) * qq) + jj;
    const int m0 = (wg / NBY) * 128;
    const int n0 = (wg % NBY) * 128;

    // B staging (waves 2,3): pre-swizzled global source, linear LDS dest
    const ushort_t* gB = (wave == 2) ? Bh : Bl;
    const int chunk_sw = (lane & 3) ^ ((lane >> 3) & 3);
    const size_t rowbB = (size_t)KC * 2;
    const char* gsrcB = (const char*)gB +
                        (size_t)(n0 + (lane >> 2)) * rowbB + (size_t)chunk_sw * 16;

    // A staging (all 256 threads): 4 x uint4 (16 packed elems) per K-tile
    const int r0 = tid >> 3, c4 = tid & 7;
    const int ch = (c4 >> 1) ^ ((r0 >> 1) & 3);     // swizzled 16B slot
    const int aoff = r0 * 64 + ch * 16 + (c4 & 1) * 8;
    const uint32_t* aSrc = Apk + (size_t)(m0 + r0) * KC + c4 * 4;

    const int wm = wave >> 1, wn = wave & 1;
    const int r4 = lane & 15, kg = lane >> 4;
    const int slot = kg ^ ((r4 >> 1) & 3);
    const int fA = (wm * 64 + r4) * 64 + slot * 16;
    const int fB = (wn * 64 + r4) * 64 + slot * 16;

    f32x4 acc[4][4];
#pragma unroll
    for (int i = 0; i < 4; ++i)
#pragma unroll
        for (int j = 0; j < 4; ++j) acc[i][j] = (f32x4){0.f, 0.f, 0.f, 0.f};

    auto issueB = [&](int ks, int bbuf) {
        if (wave >= 2) {
#pragma unroll
            for (int i = 0; i < 8; ++i) {
                __builtin_amdgcn_global_load_lds(
                    (const __attribute__((address_space(1))) uint32_t*)(
                        gsrcB + (size_t)i * 16 * rowbB + (size_t)ks * 64),
                    (__attribute__((address_space(3))) uint32_t*)(
                        lds + 32768 + bbuf * 16384 + (wave - 2) * 8192 + i * 1024),
                    16, 0, 0);
            }
        }
    };
    auto loadA = [&](int ks, uint4* R) {
#pragma unroll
        for (int i = 0; i < 4; ++i)
            R[i] = *reinterpret_cast<const uint4*>(
                aSrc + (size_t)i * 32 * KC + (size_t)ks * 32);
    };
    auto writeA = [&](const uint4* R, int abuf) {
#pragma unroll
        for (int i = 0; i < 4; ++i) {
            uint32_t hi01 = __builtin_amdgcn_perm(R[i].y, R[i].x, 0x05040100u);
            uint32_t lo01 = __builtin_amdgcn_perm(R[i].y, R[i].x, 0x07060302u);
            uint32_t hi23 = __builtin_amdgcn_perm(R[i].w, R[i].z, 0x05040100u);
            uint32_t lo23 = __builtin_amdgcn_perm(R[i].w, R[i].z, 0x07060302u);
            *reinterpret_cast<uint2*>(lds + abuf * 16384 + aoff + i * 2048) =
                make_uint2(hi01, hi23);
            *reinterpret_cast<uint2*>(lds + abuf * 16384 + 8192 + aoff + i * 2048) =
                make_uint2(lo01, lo23);
        }
    };
    auto compute = [&](int abuf, int bbuf) {
        short8 ah[4], al[4], bh[4], bl[4];
#pragma unroll
        for (int i = 0; i < 4; ++i) {
            ah[i] = *(const short8*)(lds + abuf * 16384 + fA + i * 1024);
            al[i] = *(const short8*)(lds + abuf * 16384 + 8192 + fA + i * 1024);
            bh[i] = *(const short8*)(lds + 32768 + bbuf * 16384 + fB + i * 1024);
            bl[i] = *(const short8*)(lds + 32768 + bbuf * 16384 + 8192 + fB + i * 1024);
        }
#pragma unroll
        for (int i = 0; i < 4; ++i)
#pragma unroll
            for (int j = 0; j < 4; ++j) {
                acc[i][j] = __builtin_amdgcn_mfma_f32_16x16x32_bf16(
                    ah[i], bh[j], acc[i][j], 0, 0, 0);
                acc[i][j] = __builtin_amdgcn_mfma_f32_16x16x32_bf16(
                    ah[i], bl[j], acc[i][j], 0, 0, 0);
                acc[i][j] = __builtin_amdgcn_mfma_f32_16x16x32_bf16(
                    al[i], bh[j], acc[i][j], 0, 0, 0);
            }
    };
    auto bar = [&]() {
        asm volatile("s_waitcnt lgkmcnt(0)" ::: "memory");
        __builtin_amdgcn_s_barrier();
        __builtin_amdgcn_sched_barrier(0);
    };

    uint4 R0[4], R1[4];
    // prologue: B(0)->Bbuf0, B(1)->Bbuf1; A(0)->R0, A(1)->R1; A(0)->Abuf0
    issueB(0, 0);
    issueB(1, 1);
    loadA(0, R0);
    loadA(1, R1);
    writeA(R0, 0);   // implicit vmcnt wait retires B(0),B(1),A(0)
    bar();

    int cB = 0;  // B-buf of tile s (s even at loop top)
    for (int s = 0; s + 3 < KSTEPS; s += 2) {
        int cB1 = cB + 1; if (cB1 == 3) cB1 = 0;
        int cB2 = cB1 + 1; if (cB2 == 3) cB2 = 0;
        // phase s (even, abuf 0)
        issueB(s + 2, cB2);
        loadA(s + 2, R0);
        compute(0, cB);
        writeA(R1, 1);   // A(s+1) -> abuf1; retires B(s+1)+A(s+1)
        bar();
        // phase s+1 (odd, abuf 1)
        issueB(s + 3, cB);
        loadA(s + 3, R1);
        compute(1, cB1);
        writeA(R0, 0);   // A(s+2) -> abuf0; retires B(s+2)+A(s+2)
        bar();
        cB = cB2;
    }
    int cB1 = cB + 1; if (cB1 == 3) cB1 = 0;
    // phase KSTEPS-2 (even)
    compute(0, cB);
    writeA(R1, 1);       // A(KSTEPS-1) -> abuf1; retires B(KSTEPS-1)
    bar();
    // phase KSTEPS-1 (odd)
    compute(1, cB1);

    // epilogue: C/D layout col=lane&15, row=(lane>>4)*4+reg
#pragma unroll
    for (int i = 0; i < 4; ++i)
#pragma unroll
        for (int j = 0; j < 4; ++j)
#pragma unroll
            for (int r = 0; r < 4; ++r) {
                int row = m0 + wm * 64 + i * 16 + kg * 4 + r;
                int col = n0 + wn * 64 + j * 16 + r4;
                C[(size_t)row * NC + col] = acc[i][j][r];
            }
}

extern "C" void kernel_launch(void* const* d_in, const int* in_sizes, int n_in,
                              void* d_out, int out_size, void* d_ws,
                              size_t ws_size, hipStream_t stream) {
    const float* inputs = (const float*)d_in[0];  // [500,32,512]
    const float* W1 = (const float*)d_in[1];      // [1024,512]
    const float* W2 = (const float*)d_in[2];      // [512,1024]
    float* out = (float*)d_out;                   // [500,32,512]
    char* ws = (char*)d_ws;

    // workspace (bytes):
    //  region A [0, 65,536,000): s0 packed u32 (32.77MB); later s1 packed (65.54MB)
    //  region B [65,536,000, 131,072,000): x1 f32 (65.54MB); later x2 f32
    //  weights  [131,072,000, 135,266,304): w1h w1l w2h w2l (1MB each)
    uint32_t* s0 = (uint32_t*)ws;
    uint32_t* s1 = (uint32_t*)ws;             // s0 dead after gemm1
    float*    x1 = (float*)(ws + 65536000);
    float*    x2 = (float*)(ws + 65536000);   // x1 dead after scan1
    ushort_t* w1h = (ushort_t*)(ws + 131072000);
    ushort_t* w1l = (ushort_t*)(ws + 132120576);
    ushort_t* w2h = (ushort_t*)(ws + 133169152);
    ushort_t* w2l = (ushort_t*)(ws + 134217728);

    // 1) layer-0 recurrence -> packed sigma, fused with weight split
    scan0_wsplit<<<256 + 8192, 64, 0, stream>>>(inputs, s0, W1, W2,
                                                w1h, w1l, w2h, w2l);
    // 2) X1 = S0 @ (20*W1)^T -> f32 [16000,1024]
    gemm_x3<8, N0><<<1000, 256, 0, stream>>>(s0, w1h, w1l, x1);
    // 3) layer-1 recurrence -> packed sigma
    scan_mid<N1><<<512, 64, 0, stream>>>(x1, s1);
    // 4) X2 = S1 @ (20*W2)^T -> f32 [16000,512]
    gemm_x3<4, N1><<<500, 256, 0, stream>>>(s1, w2h, w2l, x2);
    // 5) layer-2 recurrence -> spikes (20*sigma) -> out
    scan_last<<<256, 64, 0, stream>>>(x2, out);
}